// Round 3
// baseline (214.324 us; speedup 1.0000x reference)
//
#include <hip/hip_runtime.h>
#include <hip/hip_bf16.h>

#define HIDDEN 256
#define NB 4            // batches
#define NQ 200          // queries
#define MT 13           // m-tiles of 16 (208 padded rows)
#define HW 65536        // 256*256 pixels
#define KSTEPS 8        // 256 / 32
#define NPB 128         // pixels per gemm block
#define GT 512          // gemm threads (8 waves)

typedef __attribute__((ext_vector_type(8))) __bf16 bf16x8;
typedef __attribute__((ext_vector_type(4))) float f32x4;

// async global->LDS, 16 B per lane; LDS dest = wave-uniform base + lane*16
__device__ __forceinline__ void gload_lds16(const float* g, float* l) {
    __builtin_amdgcn_global_load_lds(
        (const __attribute__((address_space(1))) void*)g,
        (__attribute__((address_space(3))) void*)l, 16, 0, 0);
}

#define WAITVM(N) asm volatile("s_waitcnt vmcnt(" #N ")" ::: "memory")
__device__ __forceinline__ void wait_vm(int n) {   // n is compile-time after unroll
    switch (n) {
        case 0:  WAITVM(0);  break;
        case 2:  WAITVM(2);  break;
        case 4:  WAITVM(4);  break;
        case 6:  WAITVM(6);  break;
        case 8:  WAITVM(8);  break;
        case 10: WAITVM(10); break;
        case 12: WAITVM(12); break;
        default: WAITVM(14); break;
    }
}

__device__ __forceinline__ void hard_barrier() {
    __builtin_amdgcn_sched_barrier(0);
    __builtin_amdgcn_s_barrier();
    __builtin_amdgcn_sched_barrier(0);
}

// ---------------------------------------------------------------------------
// Kernel 1: mask_embed = (relu(q @ w1^T + b1)) @ w2^T + b2, f32 precision.
// Writes result as bf16 in MFMA 16x16x32 A-fragment order into d_ws.
// A_ws layout: [b][mt][ks][lane(64)][j(8)] bf16,
//   element (row = mt*16 + (lane&15), k = ks*32 + (lane>>4)*8 + j)
// (unchanged from round 2)
// ---------------------------------------------------------------------------
__global__ __launch_bounds__(1024)
void mlp_pack(const float* __restrict__ queries,
              const float* __restrict__ w1, const float* __restrict__ b1,
              const float* __restrict__ w2, const float* __restrict__ b2,
              __bf16* __restrict__ A_ws)
{
    __shared__ float qh[16][HIDDEN];
    __shared__ float wb[HIDDEN][33];
    const int blk = blockIdx.x;
    const int b = blk / MT, mt = blk % MT;
    const int tid = threadIdx.x;

    for (int idx = tid; idx < 16 * HIDDEN; idx += 1024) {
        int r = idx >> 8, c = idx & 255;
        int q = mt * 16 + r;
        qh[r][c] = (q < NQ) ? queries[((size_t)b * NQ + q) * HIDDEN + c] : 0.f;
    }
    __syncthreads();

    const int t  = tid & 255;
    const int rq = tid >> 8;
    const int sr = tid >> 2;
    const int si = tid & 3;

    float h[4];
    #pragma unroll
    for (int r = 0; r < 4; ++r) h[r] = b1[t];
    for (int cc = 0; cc < 8; ++cc) {
        const float* src = w1 + (size_t)sr * HIDDEN + cc * 32;
        float4 va = *reinterpret_cast<const float4*>(src + si * 4);
        float4 vb = *reinterpret_cast<const float4*>(src + 16 + si * 4);
        wb[sr][si*4+0] = va.x; wb[sr][si*4+1] = va.y;
        wb[sr][si*4+2] = va.z; wb[sr][si*4+3] = va.w;
        wb[sr][16+si*4+0] = vb.x; wb[sr][16+si*4+1] = vb.y;
        wb[sr][16+si*4+2] = vb.z; wb[sr][16+si*4+3] = vb.w;
        __syncthreads();
        #pragma unroll
        for (int cl = 0; cl < 32; ++cl) {
            float w = wb[t][cl];
            #pragma unroll
            for (int r = 0; r < 4; ++r)
                h[r] = fmaf(qh[rq * 4 + r][cc * 32 + cl], w, h[r]);
        }
        __syncthreads();
    }

    #pragma unroll
    for (int r = 0; r < 4; ++r) qh[rq * 4 + r][t] = fmaxf(h[r], 0.f);
    __syncthreads();

    float me[4];
    #pragma unroll
    for (int r = 0; r < 4; ++r) me[r] = b2[t];
    for (int cc = 0; cc < 8; ++cc) {
        const float* src = w2 + (size_t)sr * HIDDEN + cc * 32;
        float4 va = *reinterpret_cast<const float4*>(src + si * 4);
        float4 vb = *reinterpret_cast<const float4*>(src + 16 + si * 4);
        wb[sr][si*4+0] = va.x; wb[sr][si*4+1] = va.y;
        wb[sr][si*4+2] = va.z; wb[sr][si*4+3] = va.w;
        wb[sr][16+si*4+0] = vb.x; wb[sr][16+si*4+1] = vb.y;
        wb[sr][16+si*4+2] = vb.z; wb[sr][16+si*4+3] = vb.w;
        __syncthreads();
        #pragma unroll
        for (int cl = 0; cl < 32; ++cl) {
            float w = wb[t][cl];
            #pragma unroll
            for (int r = 0; r < 4; ++r)
                me[r] = fmaf(qh[rq * 4 + r][cc * 32 + cl], w, me[r]);
        }
        __syncthreads();
    }

    const int ks = t >> 5, g = (t >> 3) & 3, j = t & 7;
    #pragma unroll
    for (int r = 0; r < 4; ++r) {
        int row = rq * 4 + r;
        int q = mt * 16 + row;
        float v = (q < NQ) ? me[r] : 0.f;
        int lane = row + 16 * g;
        size_t addr = ((size_t)((b * MT + mt) * KSTEPS + ks)) * 512 + (size_t)lane * 8 + j;
        A_ws[addr] = (__bf16)v;
    }
}

// ---------------------------------------------------------------------------
// Kernel 2: pred[b][q][n] = sum_c me[b][q][c] * mf[b][c][n]
// Full-panel burst design: block = one batch x 128-pixel tile x all 208 q.
// 8 waves; wave wv owns m-tiles {wv, wv+8} x all 8 n-frags.
//  - A frags (16 per wave, 64 VGPR) loaded from L2 FIRST (oldest vmem ops).
//  - Entire B panel (256k x 128n f32 = 128 KB LDS) staged via 16
//    global_load_lds ops per wave, issued in K-step order.
//  - Iter t: s_waitcnt vmcnt(2*(7-t)) + raw s_barrier -> step-t rows ready;
//    no buffer reuse, no mid-loop drains, loads stay in flight throughout.
// grid: NB * (HW/128) = 2048 blocks.
// ---------------------------------------------------------------------------
__global__ __launch_bounds__(GT, 2)
void mask_gemm(const float* __restrict__ mf,
               const __bf16* __restrict__ A_ws,
               float* __restrict__ out)
{
    extern __shared__ float Bs[];      // [256][NPB] f32 = 128 KB

    const int bid  = blockIdx.x;
    const int b    = bid >> 9;         // 512 tiles per batch
    const int tile = bid & 511;
    const int n0   = tile * NPB;
    const int tid  = threadIdx.x;
    const int ln   = tid & 63, wv = tid >> 6;
    const int l15  = ln & 15, lg = ln >> 4;

    const float*  mfb = mf + (size_t)b * HIDDEN * HW + n0;
    const __bf16* Ab  = A_ws + (size_t)b * (MT * KSTEPS * 512);

    // ---- A fragments -> registers (MUST be issued before staging ops) ----
    bf16x8 Af[2][KSTEPS];
    #pragma unroll
    for (int i = 0; i < 2; ++i) {
        const int mt  = wv + 8 * i;
        const int mtc = (mt < MT) ? mt : (MT - 1);   // clamp; guarded at MFMA
        #pragma unroll
        for (int ks = 0; ks < KSTEPS; ++ks)
            Af[i][ks] = *reinterpret_cast<const bf16x8*>(
                Ab + ((size_t)(mtc * KSTEPS + ks)) * 512 + (size_t)ln * 8);
    }
    __builtin_amdgcn_sched_barrier(0);   // pin: A loads older than stage ops

    // ---- burst-stage the whole B panel, in step order (2 ops/wave/step) ----
    #pragma unroll
    for (int t = 0; t < KSTEPS; ++t) {
        #pragma unroll
        for (int o = 0; o < 2; ++o) {
            const int r0 = t * 32 + wv * 4 + o * 2;          // 2 rows per op
            const float* g = mfb + (size_t)(r0 + (ln >> 5)) * HW + (ln & 31) * 4;
            gload_lds16(g, &Bs[(size_t)r0 * NPB]);
        }
    }
    __builtin_amdgcn_sched_barrier(0);

    f32x4 acc[2][8];
    #pragma unroll
    for (int i = 0; i < 2; ++i)
        #pragma unroll
        for (int f = 0; f < 8; ++f)
            acc[i][f] = (f32x4){0.f, 0.f, 0.f, 0.f};

    // ---- K loop: counted vmcnt, raw barrier, no reuse hazards ----
    #pragma unroll
    for (int t = 0; t < KSTEPS; ++t) {
        wait_vm(2 * (7 - t));          // step-t rows written (own ops), A done
        hard_barrier();                // all waves' step-t rows visible

        bf16x8 bfr[8];
        #pragma unroll
        for (int f = 0; f < 8; ++f) {
            #pragma unroll
            for (int j = 0; j < 8; ++j)
                bfr[f][j] = (__bf16)Bs[(size_t)(t * 32 + lg * 8 + j) * NPB
                                       + f * 16 + l15];
        }
        #pragma unroll
        for (int i = 0; i < 2; ++i) {
            if (wv + 8 * i < MT) {
                #pragma unroll
                for (int f = 0; f < 8; ++f)
                    acc[i][f] = __builtin_amdgcn_mfma_f32_16x16x32_bf16(
                        Af[i][t], bfr[f], acc[i][f], 0, 0, 0);
            }
        }
    }

    // ---- epilogue: 7 passes of 2 m-tiles; LDS transpose -> 512B row stores ----
    float* outb = out + (size_t)b * NQ * HW + n0;
    #pragma unroll
    for (int p = 0; p < 7; ++p) {
        asm volatile("s_waitcnt lgkmcnt(0)" ::: "memory");
        hard_barrier();                          // prior pass reads done
        #pragma unroll
        for (int u = 0; u < 2; ++u) {
            const int mt = 2 * p + u;            // owner wave = mt & 7
            if (mt < MT && (mt & 7) == wv) {
                const int i = mt >> 3;
                #pragma unroll
                for (int f = 0; f < 8; ++f)
                    #pragma unroll
                    for (int r = 0; r < 4; ++r)
                        Bs[(size_t)(u * 16 + lg * 4 + r) * NPB + f * 16 + l15] =
                            acc[i][f][r];
            }
        }
        asm volatile("s_waitcnt lgkmcnt(0)" ::: "memory");
        hard_barrier();                          // writes visible
        // store 32 rows x 128 f32 = 1024 float4; 512 thr x 2
        #pragma unroll
        for (int s = 0; s < 2; ++s) {
            const int idx = tid + s * GT;
            const int row = idx >> 5, c4 = (idx & 31) << 2;
            const int q = p * 32 + row;
            if (q < NQ) {
                float4 v = *reinterpret_cast<const float4*>(&Bs[(size_t)row * NPB + c4]);
                *reinterpret_cast<float4*>(outb + (size_t)q * HW + c4) = v;
            }
        }
    }
}

// ---------------------------------------------------------------------------
extern "C" void kernel_launch(void* const* d_in, const int* in_sizes, int n_in,
                              void* d_out, int out_size, void* d_ws, size_t ws_size,
                              hipStream_t stream)
{
    const float* queries = (const float*)d_in[0];
    const float* mf      = (const float*)d_in[1];
    const float* w1      = (const float*)d_in[2];
    const float* b1      = (const float*)d_in[3];
    const float* w2      = (const float*)d_in[4];
    const float* b2      = (const float*)d_in[5];
    float*  out  = (float*)d_out;
    __bf16* A_ws = (__bf16*)d_ws;   // 4*13*8*512*2 = 425,984 B

    // allow 128 KB dynamic LDS (idempotent; not a stream op -> capture-safe)
    hipFuncSetAttribute((const void*)mask_gemm,
                        hipFuncAttributeMaxDynamicSharedMemorySize,
                        256 * NPB * 4);

    hipLaunchKernelGGL(mlp_pack, dim3(NB * MT), dim3(1024), 0, stream,
                       queries, w1, b1, w2, b2, A_ws);
    hipLaunchKernelGGL(mask_gemm, dim3(NB * (HW / NPB)), dim3(GT),
                       256 * NPB * 4, stream,
                       mf, A_ws, out);
}

// Round 4
// 163.969 us; speedup vs baseline: 1.3071x; 1.3071x over previous
//
#include <hip/hip_runtime.h>
#include <hip/hip_bf16.h>

#define HIDDEN 256
#define NB 4            // batches
#define NQ 200          // queries
#define MT 13           // m-tiles of 16 (208 padded rows)
#define HW 65536        // 256*256 pixels
#define KSTEPS 8        // 256 / 32
#define NPB 128         // pixels per gemm block
#define GT 512          // gemm threads (8 waves)

typedef __attribute__((ext_vector_type(8))) __bf16 bf16x8;
typedef __attribute__((ext_vector_type(4))) float f32x4;

#define WAIT_LGKM0() asm volatile("s_waitcnt lgkmcnt(0)" ::: "memory")
__device__ __forceinline__ void hard_barrier() {
    __builtin_amdgcn_sched_barrier(0);
    __builtin_amdgcn_s_barrier();
    __builtin_amdgcn_sched_barrier(0);
}

// ---------------------------------------------------------------------------
// Kernel 1: mask_embed MLP -> bf16 A-fragments in d_ws (unchanged, verified).
// A_ws layout: [b][mt][ks][lane(64)][j(8)] bf16,
//   element (row = mt*16 + (lane&15), k = ks*32 + (lane>>4)*8 + j)
// ---------------------------------------------------------------------------
__global__ __launch_bounds__(1024)
void mlp_pack(const float* __restrict__ queries,
              const float* __restrict__ w1, const float* __restrict__ b1,
              const float* __restrict__ w2, const float* __restrict__ b2,
              __bf16* __restrict__ A_ws)
{
    __shared__ float qh[16][HIDDEN];
    __shared__ float wb[HIDDEN][33];
    const int blk = blockIdx.x;
    const int b = blk / MT, mt = blk % MT;
    const int tid = threadIdx.x;

    for (int idx = tid; idx < 16 * HIDDEN; idx += 1024) {
        int r = idx >> 8, c = idx & 255;
        int q = mt * 16 + r;
        qh[r][c] = (q < NQ) ? queries[((size_t)b * NQ + q) * HIDDEN + c] : 0.f;
    }
    __syncthreads();

    const int t  = tid & 255;
    const int rq = tid >> 8;
    const int sr = tid >> 2;
    const int si = tid & 3;

    float h[4];
    #pragma unroll
    for (int r = 0; r < 4; ++r) h[r] = b1[t];
    for (int cc = 0; cc < 8; ++cc) {
        const float* src = w1 + (size_t)sr * HIDDEN + cc * 32;
        float4 va = *reinterpret_cast<const float4*>(src + si * 4);
        float4 vb = *reinterpret_cast<const float4*>(src + 16 + si * 4);
        wb[sr][si*4+0] = va.x; wb[sr][si*4+1] = va.y;
        wb[sr][si*4+2] = va.z; wb[sr][si*4+3] = va.w;
        wb[sr][16+si*4+0] = vb.x; wb[sr][16+si*4+1] = vb.y;
        wb[sr][16+si*4+2] = vb.z; wb[sr][16+si*4+3] = vb.w;
        __syncthreads();
        #pragma unroll
        for (int cl = 0; cl < 32; ++cl) {
            float w = wb[t][cl];
            #pragma unroll
            for (int r = 0; r < 4; ++r)
                h[r] = fmaf(qh[rq * 4 + r][cc * 32 + cl], w, h[r]);
        }
        __syncthreads();
    }

    #pragma unroll
    for (int r = 0; r < 4; ++r) qh[rq * 4 + r][t] = fmaxf(h[r], 0.f);
    __syncthreads();

    float me[4];
    #pragma unroll
    for (int r = 0; r < 4; ++r) me[r] = b2[t];
    for (int cc = 0; cc < 8; ++cc) {
        const float* src = w2 + (size_t)sr * HIDDEN + cc * 32;
        float4 va = *reinterpret_cast<const float4*>(src + si * 4);
        float4 vb = *reinterpret_cast<const float4*>(src + 16 + si * 4);
        wb[sr][si*4+0] = va.x; wb[sr][si*4+1] = va.y;
        wb[sr][si*4+2] = va.z; wb[sr][si*4+3] = va.w;
        wb[sr][16+si*4+0] = vb.x; wb[sr][16+si*4+1] = vb.y;
        wb[sr][16+si*4+2] = vb.z; wb[sr][16+si*4+3] = vb.w;
        __syncthreads();
        #pragma unroll
        for (int cl = 0; cl < 32; ++cl) {
            float w = wb[t][cl];
            #pragma unroll
            for (int r = 0; r < 4; ++r)
                me[r] = fmaf(qh[rq * 4 + r][cc * 32 + cl], w, me[r]);
        }
        __syncthreads();
    }

    const int ks = t >> 5, g = (t >> 3) & 3, j = t & 7;
    #pragma unroll
    for (int r = 0; r < 4; ++r) {
        int row = rq * 4 + r;
        int q = mt * 16 + row;
        float v = (q < NQ) ? me[r] : 0.f;
        int lane = row + 16 * g;
        size_t addr = ((size_t)((b * MT + mt) * KSTEPS + ks)) * 512 + (size_t)lane * 8 + j;
        A_ws[addr] = (__bf16)v;
    }
}

// ---------------------------------------------------------------------------
// Kernel 2: pred[b][q][n] = sum_c me[b][q][c] * mf[b][c][n]
// v4: bf16 transposed+swizzled B panel in 64 KB LDS, 2 blocks/CU.
//  - Staging: lane loads a k-run of 8 via 8 coalesced 256-B row loads,
//    cvt f32->bf16 in regs, ONE ds_write_b128 to Bt[n][k] (swizzled).
//  - K-loop (barrier-free): wave owns mt {wv, wv+8}; A frags double-buffered
//    from global (L2-resident); B frags = 8 x ds_read_b128 per step.
//  - LDS element (n,k) at byte: n*512 + (((k>>3) ^ (n&7))*16) + (k&7)*2
// grid: NB * (HW/128) = 2048 blocks, 512 threads, 2 blocks/CU.
// ---------------------------------------------------------------------------
__global__ __launch_bounds__(GT, 4)
void mask_gemm(const float* __restrict__ mf,
               const __bf16* __restrict__ A_ws,
               float* __restrict__ out)
{
    __shared__ char smem[65536];       // Bt bf16 [128 n][256 k] swizzled; reused as f32 scratch

    const int bid  = blockIdx.x;
    const int b    = bid >> 9;         // 512 tiles per batch
    const int tile = bid & 511;
    const int n0   = tile * NPB;
    const int tid  = threadIdx.x;
    const int ln   = tid & 63, wv = tid >> 6;
    const int l15  = ln & 15, lg = ln >> 4;
    const bool has2 = (wv + 8) < MT;

    const float*  mfb = mf + (size_t)b * HIDDEN * HW + n0;
    const __bf16* Ab  = A_ws + (size_t)b * (MT * KSTEPS * 512);

    // ---- stage: wave wv owns k rows [wv*32, wv*32+32), both 64-col halves ----
    #pragma unroll
    for (int ch = 0; ch < 2; ++ch) {
        const int n = ch * 64 + ln;            // column within tile (0..127)
        #pragma unroll
        for (int kb = 0; kb < 4; ++kb) {
            const int k0 = wv * 32 + kb * 8;   // k-run base
            float v[8];
            #pragma unroll
            for (int j = 0; j < 8; ++j)
                v[j] = mfb[(size_t)(k0 + j) * HW + n];
            bf16x8 pk;
            #pragma unroll
            for (int j = 0; j < 8; ++j) pk[j] = (__bf16)v[j];
            const int u = k0 >> 3;             // 16B k-unit index
            const int off = n * 512 + ((u ^ (n & 7)) << 4);
            *reinterpret_cast<bf16x8*>(&smem[off]) = pk;
        }
    }
    WAIT_LGKM0();
    hard_barrier();                            // full panel visible

    // ---- K loop: barrier-free, A double-buffered from global ----
    f32x4 acc[2][8];
    #pragma unroll
    for (int i = 0; i < 2; ++i)
        #pragma unroll
        for (int f = 0; f < 8; ++f)
            acc[i][f] = (f32x4){0.f, 0.f, 0.f, 0.f};

    bf16x8 af[2][2];
    af[0][0] = *reinterpret_cast<const bf16x8*>(
        Ab + ((size_t)(wv * KSTEPS + 0)) * 512 + (size_t)ln * 8);
    if (has2)
        af[0][1] = *reinterpret_cast<const bf16x8*>(
            Ab + ((size_t)((wv + 8) * KSTEPS + 0)) * 512 + (size_t)ln * 8);

    const int swz = l15 & 7;                   // lane's swizzle key (f-independent)
    #pragma unroll
    for (int t = 0; t < KSTEPS; ++t) {
        const int cb = t & 1, nb = cb ^ 1;     // compile-time after unroll
        if (t + 1 < KSTEPS) {
            af[nb][0] = *reinterpret_cast<const bf16x8*>(
                Ab + ((size_t)(wv * KSTEPS + t + 1)) * 512 + (size_t)ln * 8);
            if (has2)
                af[nb][1] = *reinterpret_cast<const bf16x8*>(
                    Ab + ((size_t)((wv + 8) * KSTEPS + t + 1)) * 512 + (size_t)ln * 8);
        }
        #pragma unroll
        for (int fg = 0; fg < 2; ++fg) {
            bf16x8 bf[4];
            #pragma unroll
            for (int f2 = 0; f2 < 4; ++f2) {
                const int f = fg * 4 + f2;
                const int off = (f * 16 + l15) * 512 + (((t * 4 + lg) ^ swz) << 4);
                bf[f2] = *reinterpret_cast<const bf16x8*>(&smem[off]);
            }
            #pragma unroll
            for (int f2 = 0; f2 < 4; ++f2) {
                acc[0][fg * 4 + f2] = __builtin_amdgcn_mfma_f32_16x16x32_bf16(
                    af[cb][0], bf[f2], acc[0][fg * 4 + f2], 0, 0, 0);
                if (has2)
                    acc[1][fg * 4 + f2] = __builtin_amdgcn_mfma_f32_16x16x32_bf16(
                        af[cb][1], bf[f2], acc[1][fg * 4 + f2], 0, 0, 0);
            }
        }
    }

    // ---- epilogue: 7 passes of 2 m-tiles; LDS transpose -> 512B row stores ----
    float* scr = reinterpret_cast<float*>(smem);   // [32][132] f32 (padded)
    float* outb = out + (size_t)b * NQ * HW + n0;
    #pragma unroll
    for (int p = 0; p < 7; ++p) {
        WAIT_LGKM0();
        hard_barrier();                        // prior pass reads (or K-loop) done
        #pragma unroll
        for (int u = 0; u < 2; ++u) {
            const int mt = 2 * p + u;
            if (mt < MT && (mt & 7) == wv) {
                const int i = mt >> 3;
                #pragma unroll
                for (int f = 0; f < 8; ++f)
                    #pragma unroll
                    for (int r = 0; r < 4; ++r)
                        scr[(u * 16 + lg * 4 + r) * 132 + f * 16 + l15] =
                            acc[i][f][r];
            }
        }
        WAIT_LGKM0();
        hard_barrier();                        // transpose writes visible
        #pragma unroll
        for (int s = 0; s < 2; ++s) {
            const int idx = tid + s * GT;
            const int row = idx >> 5, c4 = (idx & 31) << 2;
            const int q = p * 32 + row;
            if (q < NQ) {
                float4 v = *reinterpret_cast<const float4*>(&scr[row * 132 + c4]);
                *reinterpret_cast<float4*>(outb + (size_t)q * HW + c4) = v;
            }
        }
    }
}

// ---------------------------------------------------------------------------
extern "C" void kernel_launch(void* const* d_in, const int* in_sizes, int n_in,
                              void* d_out, int out_size, void* d_ws, size_t ws_size,
                              hipStream_t stream)
{
    const float* queries = (const float*)d_in[0];
    const float* mf      = (const float*)d_in[1];
    const float* w1      = (const float*)d_in[2];
    const float* b1      = (const float*)d_in[3];
    const float* w2      = (const float*)d_in[4];
    const float* b2      = (const float*)d_in[5];
    float*  out  = (float*)d_out;
    __bf16* A_ws = (__bf16*)d_ws;   // 4*13*8*512*2 = 425,984 B

    hipLaunchKernelGGL(mlp_pack, dim3(NB * MT), dim3(1024), 0, stream,
                       queries, w1, b1, w2, b2, A_ws);
    hipLaunchKernelGGL(mask_gemm, dim3(NB * (HW / NPB)), dim3(GT), 0, stream,
                       mf, A_ws, out);
}